// Round 1
// baseline (2235.797 us; speedup 1.0000x reference)
//
#include <hip/hip_runtime.h>
#include <hip/hip_bf16.h>

#define N_NODES 8192
#define E_EDGES 524288
#define F_IN    256
#define NH      2
#define F_OUT   128
#define C0      256   // NH*F_OUT
#define E_TOT   (E_EDGES + N_NODES)

// ---------------- GEMM1: h[8192x256] = x[8192x256] @ W[256x256] ----------------
__global__ __launch_bounds__(256) void gemm_xw_k(const float* __restrict__ A,
                                                 const float* __restrict__ B,
                                                 float* __restrict__ C) {
  const int K = 256, NC = 256;
  __shared__ float As[16][65];  // [k][m]
  __shared__ float Bs[16][65];  // [k][n]
  int bm = blockIdx.y * 64;
  int bn = blockIdx.x * 64;
  int tid = threadIdx.x;
  int tm = (tid >> 4) << 2;
  int tn = (tid & 15) << 2;
  float acc[4][4] = {};
  for (int k0 = 0; k0 < K; k0 += 16) {
#pragma unroll
    for (int i = 0; i < 4; i++) {
      int idx = tid + i * 256;
      int m = idx >> 4, k = idx & 15;
      As[k][m] = A[(bm + m) * K + k0 + k];
    }
#pragma unroll
    for (int i = 0; i < 4; i++) {
      int idx = tid + i * 256;
      int k = idx >> 6, n = idx & 63;
      Bs[k][n] = B[(k0 + k) * NC + bn + n];
    }
    __syncthreads();
#pragma unroll
    for (int k = 0; k < 16; k++) {
      float a0 = As[k][tm], a1 = As[k][tm + 1], a2 = As[k][tm + 2], a3 = As[k][tm + 3];
      float b0 = Bs[k][tn], b1 = Bs[k][tn + 1], b2 = Bs[k][tn + 2], b3 = Bs[k][tn + 3];
      acc[0][0] += a0 * b0; acc[0][1] += a0 * b1; acc[0][2] += a0 * b2; acc[0][3] += a0 * b3;
      acc[1][0] += a1 * b0; acc[1][1] += a1 * b1; acc[1][2] += a1 * b2; acc[1][3] += a1 * b3;
      acc[2][0] += a2 * b0; acc[2][1] += a2 * b1; acc[2][2] += a2 * b2; acc[2][3] += a2 * b3;
      acc[3][0] += a3 * b0; acc[3][1] += a3 * b1; acc[3][2] += a3 * b2; acc[3][3] += a3 * b3;
    }
    __syncthreads();
  }
#pragma unroll
  for (int i = 0; i < 4; i++)
#pragma unroll
    for (int j = 0; j < 4; j++)
      C[(bm + tm + i) * NC + bn + tn + j] = acc[i][j];
}

// ---------------- attention scores: a_s[n][h], a_d[n][h] ----------------
__global__ __launch_bounds__(256) void att_scores_k(const float* __restrict__ h,
                                                    const float* __restrict__ att_src,
                                                    const float* __restrict__ att_dst,
                                                    float* __restrict__ a_s,
                                                    float* __restrict__ a_d) {
  int wave = threadIdx.x >> 6;
  int lane = threadIdx.x & 63;
  int node = blockIdx.x * 4 + wave;
  if (node >= N_NODES) return;
  const float* row = h + (size_t)node * C0;
  float s0 = 0, d0 = 0, s1 = 0, d1 = 0;
  for (int i = lane; i < F_OUT; i += 64) {
    float v0 = row[i], v1 = row[F_OUT + i];
    s0 += v0 * att_src[i];          d0 += v0 * att_dst[i];
    s1 += v1 * att_src[F_OUT + i];  d1 += v1 * att_dst[F_OUT + i];
  }
#pragma unroll
  for (int off = 32; off; off >>= 1) {
    s0 += __shfl_down(s0, off); d0 += __shfl_down(d0, off);
    s1 += __shfl_down(s1, off); d1 += __shfl_down(d1, off);
  }
  if (lane == 0) {
    a_s[node * 2] = s0;     a_d[node * 2] = d0;
    a_s[node * 2 + 1] = s1; a_d[node * 2 + 1] = d1;
  }
}

// ---------------- edge pass 1: ex = exp(leaky_relu(a_s[src]+a_d[dst])); denom[dst]+=ex ----------------
__global__ __launch_bounds__(256) void edge_exp_k(const int* __restrict__ ei,
                                                  const float* __restrict__ a_s,
                                                  const float* __restrict__ a_d,
                                                  float* __restrict__ ex,
                                                  float* __restrict__ denom) {
  int e = blockIdx.x * 256 + threadIdx.x;
  if (e >= E_TOT) return;
  int s, d;
  if (e < E_EDGES) { s = ei[e]; d = ei[E_EDGES + e]; }
  else             { s = e - E_EDGES; d = s; }
#pragma unroll
  for (int hh = 0; hh < 2; hh++) {
    float v = a_s[s * 2 + hh] + a_d[d * 2 + hh];
    v = v > 0.0f ? v : 0.2f * v;     // leaky_relu 0.2
    float x = expf(v);               // no max-subtraction: scores bounded, ratio identical
    ex[e * 2 + hh] = x;
    atomicAdd(&denom[d * 2 + hh], x);
  }
}

// ---------------- edge pass 2: gat[dst] += h[src]*alpha (wave per edge) ----------------
__global__ __launch_bounds__(256) void edge_scatter_k(const int* __restrict__ ei,
                                                      const float* __restrict__ h,
                                                      const float* __restrict__ ex,
                                                      const float* __restrict__ denom,
                                                      float* __restrict__ gat) {
  int e = blockIdx.x * 4 + (threadIdx.x >> 6);
  int lane = threadIdx.x & 63;
  if (e >= E_TOT) return;
  int s, d;
  if (e < E_EDGES) { s = ei[e]; d = ei[E_EDGES + e]; }
  else             { s = e - E_EDGES; d = s; }
  int head = lane >> 5;  // (lane*4)/128
  float alpha = ex[e * 2 + head] / (denom[d * 2 + head] + 1e-16f);
  const float4 hv = *(const float4*)(h + (size_t)s * C0 + lane * 4);
  float* gp = gat + (size_t)d * C0 + lane * 4;
  atomicAdd(gp + 0, hv.x * alpha);
  atomicAdd(gp + 1, hv.y * alpha);
  atomicAdd(gp + 2, hv.z * alpha);
  atomicAdd(gp + 3, hv.w * alpha);
}

// ---------------- fused GEMM + LayerNorm + ReLU per layer ----------------
template <int KDIM, int ODIM, bool APPLY_IN>
__global__ __launch_bounds__(256) void fused_layer_k(const float* __restrict__ in,
                                                     const float* __restrict__ bias_in,
                                                     const float* __restrict__ W,
                                                     const float* __restrict__ b,
                                                     const float* __restrict__ g,
                                                     const float* __restrict__ be,
                                                     float* __restrict__ out) {
  const int TILE = 16;
  const int GROUPS = 256 / ODIM;
  const int NPT = TILE / GROUPS;
  __shared__ float in_t[TILE][KDIM + 1];
  __shared__ float out_t[TILE][ODIM + 1];
  int tid = threadIdx.x;
  int n0 = blockIdx.x * TILE;
  for (int idx = tid; idx < TILE * KDIM; idx += 256) {
    int n = idx / KDIM, k = idx % KDIM;
    float v = in[(size_t)(n0 + n) * KDIM + k];
    if (APPLY_IN) v = fmaxf(v + bias_in[k], 0.0f);  // gat bias + input relu
    in_t[n][k] = v;
  }
  __syncthreads();
  int jj = tid % ODIM;
  int grp = tid / ODIM;
  float acc[NPT];
#pragma unroll
  for (int t = 0; t < NPT; t++) acc[t] = b[jj];
  for (int k = 0; k < KDIM; k++) {
    float w = W[k * ODIM + jj];
#pragma unroll
    for (int t = 0; t < NPT; t++) acc[t] += in_t[grp + t * GROUPS][k] * w;
  }
#pragma unroll
  for (int t = 0; t < NPT; t++) out_t[grp + t * GROUPS][jj] = acc[t];
  __syncthreads();
  // LayerNorm across ODIM, 16 threads per node
  const int TPN = 256 / TILE;   // 16
  const int JPT = ODIM / TPN;
  int node = tid / TPN;
  int ln = tid % TPN;
  float v[JPT];
  float s = 0;
#pragma unroll
  for (int q = 0; q < JPT; q++) { v[q] = out_t[node][ln + q * TPN]; s += v[q]; }
#pragma unroll
  for (int m = 1; m < TPN; m <<= 1) s += __shfl_xor(s, m);
  float mu = s / (float)ODIM;
  float vs = 0;
#pragma unroll
  for (int q = 0; q < JPT; q++) { float dd = v[q] - mu; vs += dd * dd; }
#pragma unroll
  for (int m = 1; m < TPN; m <<= 1) vs += __shfl_xor(vs, m);
  float inv = rsqrtf(vs / (float)ODIM + 1e-5f);
#pragma unroll
  for (int q = 0; q < JPT; q++) {
    int j = ln + q * TPN;
    float o = (v[q] - mu) * inv * g[j] + be[j];
    out[(size_t)(n0 + node) * ODIM + j] = fmaxf(o, 0.0f);
  }
}

// ---------------- final projection: z[n] = h2[n] @ w3 + b3 (stored float4) ----------------
__global__ __launch_bounds__(256) void final_z_k(const float* __restrict__ h2,
                                                 const float* __restrict__ w3,
                                                 const float* __restrict__ b3,
                                                 float* __restrict__ z) {
  int n = blockIdx.x * 256 + threadIdx.x;
  if (n >= N_NODES) return;
  float a0 = b3[0], a1 = b3[1], a2 = b3[2];
  const float* row = h2 + (size_t)n * 32;
#pragma unroll
  for (int k = 0; k < 32; k++) {
    float v = row[k];
    a0 += v * w3[k * 3 + 0];
    a1 += v * w3[k * 3 + 1];
    a2 += v * w3[k * 3 + 2];
  }
  float4 zz = {a0, a1, a2, 0.0f};
  ((float4*)z)[n] = zz;
}

// ---------------- cdist: out[i][j] = ||z_i - z_j|| ----------------
__global__ __launch_bounds__(256) void cdist_k(const float* __restrict__ z,
                                               float* __restrict__ out) {
  int i = blockIdx.x >> 3;
  int j0 = (((blockIdx.x & 7) << 8) + threadIdx.x) << 2;  // first of 4 nodes
  const float4 zi = ((const float4*)z)[i];
  float4 r;
  {
    float4 zj = ((const float4*)z)[j0 + 0];
    float dx = zi.x - zj.x, dy = zi.y - zj.y, dz = zi.z - zj.z;
    r.x = sqrtf(dx * dx + dy * dy + dz * dz);
  }
  {
    float4 zj = ((const float4*)z)[j0 + 1];
    float dx = zi.x - zj.x, dy = zi.y - zj.y, dz = zi.z - zj.z;
    r.y = sqrtf(dx * dx + dy * dy + dz * dz);
  }
  {
    float4 zj = ((const float4*)z)[j0 + 2];
    float dx = zi.x - zj.x, dy = zi.y - zj.y, dz = zi.z - zj.z;
    r.z = sqrtf(dx * dx + dy * dy + dz * dz);
  }
  {
    float4 zj = ((const float4*)z)[j0 + 3];
    float dx = zi.x - zj.x, dy = zi.y - zj.y, dz = zi.z - zj.z;
    r.w = sqrtf(dx * dx + dy * dy + dz * dz);
  }
  ((float4*)out)[((size_t)i * N_NODES + j0) >> 2] = r;
}

extern "C" void kernel_launch(void* const* d_in, const int* in_sizes, int n_in,
                              void* d_out, int out_size, void* d_ws, size_t ws_size,
                              hipStream_t stream) {
  const float* x        = (const float*)d_in[0];
  const int*   ei       = (const int*)d_in[1];
  const float* W_gat    = (const float*)d_in[2];
  const float* att_src  = (const float*)d_in[3];
  const float* att_dst  = (const float*)d_in[4];
  const float* bias_gat = (const float*)d_in[5];
  const float* w_a      = (const float*)d_in[6];
  const float* b_a      = (const float*)d_in[7];
  const float* g_a      = (const float*)d_in[8];
  const float* be_a     = (const float*)d_in[9];
  const float* w1       = (const float*)d_in[10];
  const float* b1       = (const float*)d_in[11];
  const float* g1       = (const float*)d_in[12];
  const float* be1      = (const float*)d_in[13];
  const float* w2       = (const float*)d_in[14];
  const float* b2       = (const float*)d_in[15];
  const float* g2       = (const float*)d_in[16];
  const float* be2      = (const float*)d_in[17];
  const float* w3       = (const float*)d_in[18];
  const float* b3       = (const float*)d_in[19];
  float* out = (float*)d_out;

  float* ws = (float*)d_ws;
  float* h     = ws;                      // 8192*256
  float* a_s   = h + 2097152;             // 8192*2
  float* a_d   = a_s + 16384;             // 8192*2
  float* ex    = a_d + 16384;             // 532480*2
  float* denom = ex + 1064960;            // 8192*2
  float* gat   = denom + 16384;           // 8192*256
  float* hA    = gat + 2097152;           // 8192*128
  float* h1    = hA + 1048576;            // 8192*64
  float* h2    = h1 + 524288;             // 8192*32
  float* z     = h2 + 262144;             // 8192*4

  // zero the atomic accumulators
  hipMemsetAsync(denom, 0, 16384 * sizeof(float), stream);
  hipMemsetAsync(gat, 0, 2097152 * sizeof(float), stream);

  // 1. h = x @ W_gat
  gemm_xw_k<<<dim3(4, 128), 256, 0, stream>>>(x, W_gat, h);
  // 2. attention scores
  att_scores_k<<<2048, 256, 0, stream>>>(h, att_src, att_dst, a_s, a_d);
  // 3. edge exp + denom
  edge_exp_k<<<E_TOT / 256, 256, 0, stream>>>(ei, a_s, a_d, ex, denom);
  // 4. scatter messages
  edge_scatter_k<<<E_TOT / 4, 256, 0, stream>>>(ei, h, ex, denom, gat);
  // 5. fused layers
  fused_layer_k<256, 128, true><<<N_NODES / 16, 256, 0, stream>>>(gat, bias_gat, w_a, b_a, g_a, be_a, hA);
  fused_layer_k<128, 64, false><<<N_NODES / 16, 256, 0, stream>>>(hA, nullptr, w1, b1, g1, be1, h1);
  fused_layer_k<64, 32, false><<<N_NODES / 16, 256, 0, stream>>>(h1, nullptr, w2, b2, g2, be2, h2);
  // 6. final projection to 3D
  final_z_k<<<N_NODES / 256, 256, 0, stream>>>(h2, w3, b3, z);
  // 7. pairwise distances
  cdist_k<<<N_NODES * 8, 256, 0, stream>>>(z, out);
}

// Round 3
// 522.892 us; speedup vs baseline: 4.2758x; 4.2758x over previous
//
#include <hip/hip_runtime.h>
#include <hip/hip_bf16.h>

#define N_NODES 8192
#define E_EDGES 524288
#define F_IN    256
#define NH      2
#define F_OUT   128
#define C0      256   // NH*F_OUT

// ---------------- GEMM1: h[8192x256] = x[8192x256] @ W[256x256] ----------------
__global__ __launch_bounds__(256) void gemm_xw_k(const float* __restrict__ A,
                                                 const float* __restrict__ B,
                                                 float* __restrict__ C) {
  const int K = 256, NC = 256;
  __shared__ float As[16][65];  // [k][m]
  __shared__ float Bs[16][65];  // [k][n]
  int bm = blockIdx.y * 64;
  int bn = blockIdx.x * 64;
  int tid = threadIdx.x;
  int tm = (tid >> 4) << 2;
  int tn = (tid & 15) << 2;
  float acc[4][4] = {};
  for (int k0 = 0; k0 < K; k0 += 16) {
#pragma unroll
    for (int i = 0; i < 4; i++) {
      int idx = tid + i * 256;
      int m = idx >> 4, k = idx & 15;
      As[k][m] = A[(bm + m) * K + k0 + k];
    }
#pragma unroll
    for (int i = 0; i < 4; i++) {
      int idx = tid + i * 256;
      int k = idx >> 6, n = idx & 63;
      Bs[k][n] = B[(k0 + k) * NC + bn + n];
    }
    __syncthreads();
#pragma unroll
    for (int k = 0; k < 16; k++) {
      float a0 = As[k][tm], a1 = As[k][tm + 1], a2 = As[k][tm + 2], a3 = As[k][tm + 3];
      float b0 = Bs[k][tn], b1 = Bs[k][tn + 1], b2 = Bs[k][tn + 2], b3 = Bs[k][tn + 3];
      acc[0][0] += a0 * b0; acc[0][1] += a0 * b1; acc[0][2] += a0 * b2; acc[0][3] += a0 * b3;
      acc[1][0] += a1 * b0; acc[1][1] += a1 * b1; acc[1][2] += a1 * b2; acc[1][3] += a1 * b3;
      acc[2][0] += a2 * b0; acc[2][1] += a2 * b1; acc[2][2] += a2 * b2; acc[2][3] += a2 * b3;
      acc[3][0] += a3 * b0; acc[3][1] += a3 * b1; acc[3][2] += a3 * b2; acc[3][3] += a3 * b3;
    }
    __syncthreads();
  }
#pragma unroll
  for (int i = 0; i < 4; i++)
#pragma unroll
    for (int j = 0; j < 4; j++)
      C[(bm + tm + i) * NC + bn + tn + j] = acc[i][j];
}

// ---------------- attention scores: a_s[n][h], a_d[n][h] ----------------
__global__ __launch_bounds__(256) void att_scores_k(const float* __restrict__ h,
                                                    const float* __restrict__ att_src,
                                                    const float* __restrict__ att_dst,
                                                    float* __restrict__ a_s,
                                                    float* __restrict__ a_d) {
  int wave = threadIdx.x >> 6;
  int lane = threadIdx.x & 63;
  int node = blockIdx.x * 4 + wave;
  if (node >= N_NODES) return;
  const float* row = h + (size_t)node * C0;
  float s0 = 0, d0 = 0, s1 = 0, d1 = 0;
  for (int i = lane; i < F_OUT; i += 64) {
    float v0 = row[i], v1 = row[F_OUT + i];
    s0 += v0 * att_src[i];          d0 += v0 * att_dst[i];
    s1 += v1 * att_src[F_OUT + i];  d1 += v1 * att_dst[F_OUT + i];
  }
#pragma unroll
  for (int off = 32; off; off >>= 1) {
    s0 += __shfl_down(s0, off); d0 += __shfl_down(d0, off);
    s1 += __shfl_down(s1, off); d1 += __shfl_down(d1, off);
  }
  if (lane == 0) {
    a_s[node * 2] = s0;     a_d[node * 2] = d0;
    a_s[node * 2 + 1] = s1; a_d[node * 2 + 1] = d1;
  }
}

// ---------------- counting sort by dst: histogram ----------------
__global__ __launch_bounds__(256) void hist_k(const int* __restrict__ ei,
                                              int* __restrict__ deg) {
  int e = blockIdx.x * 256 + threadIdx.x;
  if (e < E_EDGES) atomicAdd(&deg[ei[E_EDGES + e]], 1);
}

// ---------------- exclusive scan of 8192 degrees (single block) ----------------
__global__ __launch_bounds__(256) void scan_k(const int* __restrict__ deg,
                                              int* __restrict__ offs,
                                              int* __restrict__ cursor) {
  __shared__ int sums[256];
  int t = threadIdx.x;
  int local[32];
  int s = 0;
#pragma unroll
  for (int i = 0; i < 32; i++) { local[i] = s; s += deg[t * 32 + i]; }
  sums[t] = s;
  __syncthreads();
  for (int off = 1; off < 256; off <<= 1) {
    int u = (t >= off) ? sums[t - off] : 0;
    __syncthreads();
    if (t >= off) sums[t] += u;
    __syncthreads();
  }
  int base = sums[t] - s;   // exclusive prefix for this thread's chunk
#pragma unroll
  for (int i = 0; i < 32; i++) {
    int o = base + local[i];
    offs[t * 32 + i] = o;
    cursor[t * 32 + i] = o;
  }
  if (t == 255) offs[N_NODES] = sums[255];
}

// ---------------- scatter src ids into dst-sorted order ----------------
__global__ __launch_bounds__(256) void scatter_src_k(const int* __restrict__ ei,
                                                     int* __restrict__ cursor,
                                                     int* __restrict__ sorted_src) {
  int e = blockIdx.x * 256 + threadIdx.x;
  if (e < E_EDGES) {
    int d = ei[E_EDGES + e];
    int p = atomicAdd(&cursor[d], 1);
    sorted_src[p] = ei[e];
  }
}

// ---------------- gather: one wave per dst node, fused softmax + message agg ----------------
__global__ __launch_bounds__(256) void gat_gather_k(const int* __restrict__ sorted_src,
                                                    const int* __restrict__ offs,
                                                    const float* __restrict__ h,
                                                    const float* __restrict__ a_s,
                                                    const float* __restrict__ a_d,
                                                    float* __restrict__ gat) {
  int wave = threadIdx.x >> 6;
  int lane = threadIdx.x & 63;
  int node = blockIdx.x * 4 + wave;
  if (node >= N_NODES) return;
  int start = offs[node], end = offs[node + 1];
  float ad0 = a_d[node * 2], ad1 = a_d[node * 2 + 1];
  int head = lane >> 5;
  float4 acc = {0, 0, 0, 0};
  float den0 = 0, den1 = 0;
  for (int base = start; base < end; base += 64) {
    int idx = base + lane;
    int s = -1;
    float e0 = 0, e1 = 0;
    if (idx < end) {
      s = sorted_src[idx];
      float v0 = a_s[s * 2] + ad0;     v0 = v0 > 0.0f ? v0 : 0.2f * v0;
      float v1 = a_s[s * 2 + 1] + ad1; v1 = v1 > 0.0f ? v1 : 0.2f * v1;
      e0 = __expf(v0);
      e1 = __expf(v1);
      den0 += e0; den1 += e1;
    }
    int cnt = min(64, end - base);
    for (int j = 0; j < cnt; j++) {
      int sj = __shfl(s, j);
      float x0 = __shfl(e0, j);
      float x1 = __shfl(e1, j);
      float exh = head ? x1 : x0;
      const float4 hv = *(const float4*)(h + (size_t)sj * C0 + lane * 4);
      acc.x += hv.x * exh; acc.y += hv.y * exh;
      acc.z += hv.z * exh; acc.w += hv.w * exh;
    }
  }
  // self-loop (src = dst = node): message on all lanes, denom on lane 0 ONLY
  {
    float v0 = a_s[node * 2] + ad0;     v0 = v0 > 0.0f ? v0 : 0.2f * v0;
    float v1 = a_s[node * 2 + 1] + ad1; v1 = v1 > 0.0f ? v1 : 0.2f * v1;
    float e0 = __expf(v0), e1 = __expf(v1);
    if (lane == 0) { den0 += e0; den1 += e1; }   // R2 bug: was added by all 64 lanes
    float exh = head ? e1 : e0;
    const float4 hv = *(const float4*)(h + (size_t)node * C0 + lane * 4);
    acc.x += hv.x * exh; acc.y += hv.y * exh;
    acc.z += hv.z * exh; acc.w += hv.w * exh;
  }
  // wave-reduce denominators
#pragma unroll
  for (int off = 32; off; off >>= 1) {
    den0 += __shfl_xor(den0, off);
    den1 += __shfl_xor(den1, off);
  }
  float denh = head ? den1 : den0;
  float inv = 1.0f / (denh + 1e-16f);
  float4 o = {acc.x * inv, acc.y * inv, acc.z * inv, acc.w * inv};
  *(float4*)(gat + (size_t)node * C0 + lane * 4) = o;
}

// ---------------- fused GEMM + LayerNorm + ReLU per layer ----------------
template <int KDIM, int ODIM, bool APPLY_IN>
__global__ __launch_bounds__(256) void fused_layer_k(const float* __restrict__ in,
                                                     const float* __restrict__ bias_in,
                                                     const float* __restrict__ W,
                                                     const float* __restrict__ b,
                                                     const float* __restrict__ g,
                                                     const float* __restrict__ be,
                                                     float* __restrict__ out) {
  const int TILE = 16;
  const int GROUPS = 256 / ODIM;
  const int NPT = TILE / GROUPS;
  __shared__ float in_t[TILE][KDIM + 1];
  __shared__ float out_t[TILE][ODIM + 1];
  int tid = threadIdx.x;
  int n0 = blockIdx.x * TILE;
  for (int idx = tid; idx < TILE * KDIM; idx += 256) {
    int n = idx / KDIM, k = idx % KDIM;
    float v = in[(size_t)(n0 + n) * KDIM + k];
    if (APPLY_IN) v = fmaxf(v + bias_in[k], 0.0f);  // gat bias + input relu
    in_t[n][k] = v;
  }
  __syncthreads();
  int jj = tid % ODIM;
  int grp = tid / ODIM;
  float acc[NPT];
#pragma unroll
  for (int t = 0; t < NPT; t++) acc[t] = b[jj];
  for (int k = 0; k < KDIM; k++) {
    float w = W[k * ODIM + jj];
#pragma unroll
    for (int t = 0; t < NPT; t++) acc[t] += in_t[grp + t * GROUPS][k] * w;
  }
#pragma unroll
  for (int t = 0; t < NPT; t++) out_t[grp + t * GROUPS][jj] = acc[t];
  __syncthreads();
  // LayerNorm across ODIM, 16 threads per node
  const int TPN = 256 / TILE;   // 16
  const int JPT = ODIM / TPN;
  int node = tid / TPN;
  int ln = tid % TPN;
  float v[JPT];
  float s = 0;
#pragma unroll
  for (int q = 0; q < JPT; q++) { v[q] = out_t[node][ln + q * TPN]; s += v[q]; }
#pragma unroll
  for (int m = 1; m < TPN; m <<= 1) s += __shfl_xor(s, m);
  float mu = s / (float)ODIM;
  float vs = 0;
#pragma unroll
  for (int q = 0; q < JPT; q++) { float dd = v[q] - mu; vs += dd * dd; }
#pragma unroll
  for (int m = 1; m < TPN; m <<= 1) vs += __shfl_xor(vs, m);
  float inv = rsqrtf(vs / (float)ODIM + 1e-5f);
#pragma unroll
  for (int q = 0; q < JPT; q++) {
    int j = ln + q * TPN;
    float o = (v[q] - mu) * inv * g[j] + be[j];
    out[(size_t)(n0 + node) * ODIM + j] = fmaxf(o, 0.0f);
  }
}

// ---------------- final projection: z[n] = h2[n] @ w3 + b3 (stored float4) ----------------
__global__ __launch_bounds__(256) void final_z_k(const float* __restrict__ h2,
                                                 const float* __restrict__ w3,
                                                 const float* __restrict__ b3,
                                                 float* __restrict__ z) {
  int n = blockIdx.x * 256 + threadIdx.x;
  if (n >= N_NODES) return;
  float a0 = b3[0], a1 = b3[1], a2 = b3[2];
  const float* row = h2 + (size_t)n * 32;
#pragma unroll
  for (int k = 0; k < 32; k++) {
    float v = row[k];
    a0 += v * w3[k * 3 + 0];
    a1 += v * w3[k * 3 + 1];
    a2 += v * w3[k * 3 + 2];
  }
  float4 zz = {a0, a1, a2, 0.0f};
  ((float4*)z)[n] = zz;
}

// ---------------- cdist: out[i][j] = ||z_i - z_j|| ----------------
__global__ __launch_bounds__(256) void cdist_k(const float* __restrict__ z,
                                               float* __restrict__ out) {
  int i = blockIdx.x >> 3;
  int j0 = (((blockIdx.x & 7) << 8) + threadIdx.x) << 2;  // first of 4 nodes
  const float4 zi = ((const float4*)z)[i];
  float4 r;
  {
    float4 zj = ((const float4*)z)[j0 + 0];
    float dx = zi.x - zj.x, dy = zi.y - zj.y, dz = zi.z - zj.z;
    r.x = sqrtf(dx * dx + dy * dy + dz * dz);
  }
  {
    float4 zj = ((const float4*)z)[j0 + 1];
    float dx = zi.x - zj.x, dy = zi.y - zj.y, dz = zi.z - zj.z;
    r.y = sqrtf(dx * dx + dy * dy + dz * dz);
  }
  {
    float4 zj = ((const float4*)z)[j0 + 2];
    float dx = zi.x - zj.x, dy = zi.y - zj.y, dz = zi.z - zj.z;
    r.z = sqrtf(dx * dx + dy * dy + dz * dz);
  }
  {
    float4 zj = ((const float4*)z)[j0 + 3];
    float dx = zi.x - zj.x, dy = zi.y - zj.y, dz = zi.z - zj.z;
    r.w = sqrtf(dx * dx + dy * dy + dz * dz);
  }
  ((float4*)out)[((size_t)i * N_NODES + j0) >> 2] = r;
}

extern "C" void kernel_launch(void* const* d_in, const int* in_sizes, int n_in,
                              void* d_out, int out_size, void* d_ws, size_t ws_size,
                              hipStream_t stream) {
  const float* x        = (const float*)d_in[0];
  const int*   ei       = (const int*)d_in[1];
  const float* W_gat    = (const float*)d_in[2];
  const float* att_src  = (const float*)d_in[3];
  const float* att_dst  = (const float*)d_in[4];
  const float* bias_gat = (const float*)d_in[5];
  const float* w_a      = (const float*)d_in[6];
  const float* b_a      = (const float*)d_in[7];
  const float* g_a      = (const float*)d_in[8];
  const float* be_a     = (const float*)d_in[9];
  const float* w1       = (const float*)d_in[10];
  const float* b1       = (const float*)d_in[11];
  const float* g1       = (const float*)d_in[12];
  const float* be1      = (const float*)d_in[13];
  const float* w2       = (const float*)d_in[14];
  const float* b2       = (const float*)d_in[15];
  const float* g2       = (const float*)d_in[16];
  const float* be2      = (const float*)d_in[17];
  const float* w3       = (const float*)d_in[18];
  const float* b3       = (const float*)d_in[19];
  float* out = (float*)d_out;

  float* ws = (float*)d_ws;
  float* h     = ws;                      // 8192*256
  float* a_s   = h + 2097152;             // 8192*2
  float* a_d   = a_s + 16384;             // 8192*2
  float* gat   = a_d + 16384;             // 8192*256
  float* hA    = gat + 2097152;           // 8192*128
  float* h1    = hA + 1048576;            // 8192*64
  float* h2    = h1 + 524288;             // 8192*32
  float* z     = h2 + 262144;             // 8192*4
  int*   deg    = (int*)(z + 32768);      // 8192
  int*   offs   = deg + 8192;             // 8193 (+pad)
  int*   cursor = offs + 8200;            // 8192
  int*   sorted = cursor + 8192;          // 524288

  // zero the histogram
  hipMemsetAsync(deg, 0, N_NODES * sizeof(int), stream);

  // 1. h = x @ W_gat
  gemm_xw_k<<<dim3(4, 128), 256, 0, stream>>>(x, W_gat, h);
  // 2. attention scores
  att_scores_k<<<2048, 256, 0, stream>>>(h, att_src, att_dst, a_s, a_d);
  // 3. counting sort by dst
  hist_k<<<E_EDGES / 256, 256, 0, stream>>>(ei, deg);
  scan_k<<<1, 256, 0, stream>>>(deg, offs, cursor);
  scatter_src_k<<<E_EDGES / 256, 256, 0, stream>>>(ei, cursor, sorted);
  // 4. fused softmax + message aggregation (gather, no atomics)
  gat_gather_k<<<2048, 256, 0, stream>>>(sorted, offs, h, a_s, a_d, gat);
  // 5. fused layers
  fused_layer_k<256, 128, true><<<N_NODES / 16, 256, 0, stream>>>(gat, bias_gat, w_a, b_a, g_a, be_a, hA);
  fused_layer_k<128, 64, false><<<N_NODES / 16, 256, 0, stream>>>(hA, nullptr, w1, b1, g1, be1, h1);
  fused_layer_k<64, 32, false><<<N_NODES / 16, 256, 0, stream>>>(h1, nullptr, w2, b2, g2, be2, h2);
  // 6. final projection to 3D
  final_z_k<<<N_NODES / 256, 256, 0, stream>>>(h2, w3, b3, z);
  // 7. pairwise distances
  cdist_k<<<N_NODES * 8, 256, 0, stream>>>(z, out);
}